// Round 2
// baseline (56.812 us; speedup 1.0000x reference)
//
#include <hip/hip_runtime.h>
#include <math.h>

constexpr int T_LEN  = 8192;   // per-row length (== TREF)
constexpr int B_ROWS = 4096;
constexpr int NB     = 49;     // NBINS - 1 bins
constexpr int HDIM   = 32;
constexpr float EPSF = 1e-10f;

// ---------------- kernel 1: reference min/max -> ws[0], ws[1] ----------------
__global__ __launch_bounds__(256)
void ref_minmax_kernel(const float* __restrict__ ref, float* __restrict__ ws) {
    __shared__ float smn[256], smx[256];
    int tid = threadIdx.x;
    float mn = 3.0e38f, mx = -3.0e38f;
    const float4* r4 = (const float4*)ref;
    for (int i = tid; i < T_LEN / 4; i += 256) {
        float4 v = r4[i];
        mn = fminf(mn, fminf(fminf(v.x, v.y), fminf(v.z, v.w)));
        mx = fmaxf(mx, fmaxf(fmaxf(v.x, v.y), fmaxf(v.z, v.w)));
    }
    smn[tid] = mn; smx[tid] = mx;
    __syncthreads();
    for (int s = 128; s > 0; s >>= 1) {
        if (tid < s) {
            smn[tid] = fminf(smn[tid], smn[tid + s]);
            smx[tid] = fmaxf(smx[tid], smx[tid + s]);
        }
        __syncthreads();
    }
    if (tid == 0) { ws[0] = smn[0]; ws[1] = smx[0]; }
}

// ---------------- kernel 2: per-row KL ----------------
// One block (256 threads) per row. Row staged in LDS; reference re-binned per
// row from global (32 KB, stays hot in L2/L3).
__global__ __launch_bounds__(256)
void kl_kernel(const float* __restrict__ cur,
               const float* __restrict__ ref,
               const float* __restrict__ ws,
               float* __restrict__ kl_out) {
    __shared__ float row[T_LEN];           // 32 KB
    __shared__ unsigned hp[NB], hq[NB];
    __shared__ float rmn[4], rmx[4];

    const int b    = blockIdx.x;
    const int tid  = threadIdx.x;
    const int lane = tid & 63;
    const int wave = tid >> 6;

    if (tid < NB) { hp[tid] = 0u; hq[tid] = 0u; }

    // ---- pass 1: stage row into LDS, compute per-thread min/max ----
    const float4* src = (const float4*)(cur + (size_t)b * T_LEN);
    float4* row4 = (float4*)row;
    float mn = 3.0e38f, mx = -3.0e38f;
    #pragma unroll
    for (int i = 0; i < 8; ++i) {
        float4 v = src[tid + i * 256];
        row4[tid + i * 256] = v;
        mn = fminf(mn, fminf(fminf(v.x, v.y), fminf(v.z, v.w)));
        mx = fmaxf(mx, fmaxf(fmaxf(v.x, v.y), fmaxf(v.z, v.w)));
    }
    // wave reduce
    #pragma unroll
    for (int off = 32; off > 0; off >>= 1) {
        mn = fminf(mn, __shfl_xor(mn, off));
        mx = fmaxf(mx, __shfl_xor(mx, off));
    }
    if (lane == 0) { rmn[wave] = mn; rmx[wave] = mx; }
    __syncthreads();

    const float cmin = fminf(fminf(rmn[0], rmn[1]), fminf(rmn[2], rmn[3]));
    const float cmax = fmaxf(fmaxf(rmx[0], rmx[1]), fmaxf(rmx[2], rmx[3]));
    const float lo = fminf(ws[0], cmin);
    const float hi = fmaxf(ws[1], cmax);
    const float width = (hi - lo) / (float)NB;

    // ---- histogram current row (from LDS) ----
    #pragma unroll
    for (int i = 0; i < 8; ++i) {
        float4 v = row4[tid + i * 256];
        int i0 = min(max((int)floorf((v.x - lo) / width), 0), NB - 1);
        int i1 = min(max((int)floorf((v.y - lo) / width), 0), NB - 1);
        int i2 = min(max((int)floorf((v.z - lo) / width), 0), NB - 1);
        int i3 = min(max((int)floorf((v.w - lo) / width), 0), NB - 1);
        atomicAdd(&hq[i0], 1u);
        atomicAdd(&hq[i1], 1u);
        atomicAdd(&hq[i2], 1u);
        atomicAdd(&hq[i3], 1u);
    }
    // ---- histogram reference (from global; L2-hot) ----
    const float4* r4 = (const float4*)ref;
    #pragma unroll
    for (int i = 0; i < 8; ++i) {
        float4 v = r4[tid + i * 256];
        int i0 = min(max((int)floorf((v.x - lo) / width), 0), NB - 1);
        int i1 = min(max((int)floorf((v.y - lo) / width), 0), NB - 1);
        int i2 = min(max((int)floorf((v.z - lo) / width), 0), NB - 1);
        int i3 = min(max((int)floorf((v.w - lo) / width), 0), NB - 1);
        atomicAdd(&hp[i0], 1u);
        atomicAdd(&hp[i1], 1u);
        atomicAdd(&hp[i2], 1u);
        atomicAdd(&hp[i3], 1u);
    }
    __syncthreads();

    // ---- KL over 49 bins on wave 0 ----
    if (tid < 64) {
        const bool act = tid < NB;
        float p = 0.0f, q = 0.0f;
        if (act) {
            const float inv = 1.0f / ((float)T_LEN * width);
            p = (float)hp[tid] * inv + EPSF;
            q = (float)hq[tid] * inv + EPSF;
        }
        float P = p, Q = q;
        #pragma unroll
        for (int off = 32; off > 0; off >>= 1) {
            P += __shfl_xor(P, off);
            Q += __shfl_xor(Q, off);
        }
        float term = 0.0f;
        if (act) {
            const float pn = p / P;
            const float qn = q / Q;
            term = pn * logf(pn / qn);
        }
        #pragma unroll
        for (int off = 32; off > 0; off >>= 1) term += __shfl_xor(term, off);
        if (tid == 0) kl_out[b] = term;
    }
}

// ---------------- kernel 3: tiny MLP ----------------
// encoded[b][j] = sum_t relu(kl[b]*w1[t] + b1[t]) * w2[j][t] + b2[j]
__global__ __launch_bounds__(256)
void mlp_kernel(const float* __restrict__ kl, const float* __restrict__ w1,
                const float* __restrict__ b1, const float* __restrict__ w2,
                const float* __restrict__ b2, float* __restrict__ out) {
    __shared__ float sw1[HDIM], sb1[HDIM], sb2[HDIM], sw2t[HDIM * HDIM];
    int tid = threadIdx.x;
    if (tid < HDIM) { sw1[tid] = w1[tid]; sb1[tid] = b1[tid]; sb2[tid] = b2[tid]; }
    for (int i = tid; i < HDIM * HDIM; i += 256) {
        int j = i >> 5, t = i & 31;
        sw2t[t * HDIM + j] = w2[i];    // transpose so lanes read consecutively
    }
    __syncthreads();
    int gid = blockIdx.x * 256 + tid;
    int b = gid >> 5, j = gid & 31;
    if (b < B_ROWS) {
        float k = kl[b];
        float acc = sb2[j];
        #pragma unroll
        for (int t = 0; t < HDIM; ++t) {
            float h = fmaxf(fmaf(k, sw1[t], sb1[t]), 0.0f);
            acc = fmaf(h, sw2t[t * HDIM + j], acc);
        }
        out[(size_t)b * HDIM + j] = acc;
    }
}

extern "C" void kernel_launch(void* const* d_in, const int* in_sizes, int n_in,
                              void* d_out, int out_size, void* d_ws, size_t ws_size,
                              hipStream_t stream) {
    const float* cur = (const float*)d_in[0];
    const float* ref = (const float*)d_in[1];
    const float* w1  = (const float*)d_in[2];
    const float* b1  = (const float*)d_in[3];
    const float* w2  = (const float*)d_in[4];
    const float* b2  = (const float*)d_in[5];
    float* out = (float*)d_out;           // [0, B) = kl ; [B, B + B*H) = encoded
    float* ws  = (float*)d_ws;

    ref_minmax_kernel<<<1, 256, 0, stream>>>(ref, ws);
    kl_kernel<<<B_ROWS, 256, 0, stream>>>(cur, ref, ws, out);
    mlp_kernel<<<(B_ROWS * HDIM + 255) / 256, 256, 0, stream>>>(
        out, w1, b1, w2, b2, out + B_ROWS);
}

// Round 3
// 46.332 us; speedup vs baseline: 1.2262x; 1.2262x over previous
//
#include <hip/hip_runtime.h>
#include <math.h>

constexpr int T_LEN  = 8192;   // per-row length (== TREF)
constexpr int B_ROWS = 4096;
constexpr int NB     = 49;     // NBINS - 1 bins
constexpr int NC     = 32;     // histogram replicas (copy = lane & 31)
constexpr int HDIM   = 32;
constexpr float EPSF = 1e-10f;

// ---------------- kernel 1: reference min/max -> ws[0], ws[1] ----------------
__global__ __launch_bounds__(256)
void ref_minmax_kernel(const float* __restrict__ ref, float* __restrict__ ws) {
    __shared__ float smn[256], smx[256];
    int tid = threadIdx.x;
    float mn = 3.0e38f, mx = -3.0e38f;
    const float4* r4 = (const float4*)ref;
    for (int i = tid; i < T_LEN / 4; i += 256) {
        float4 v = r4[i];
        mn = fminf(mn, fminf(fminf(v.x, v.y), fminf(v.z, v.w)));
        mx = fmaxf(mx, fmaxf(fmaxf(v.x, v.y), fmaxf(v.z, v.w)));
    }
    smn[tid] = mn; smx[tid] = mx;
    __syncthreads();
    for (int s = 128; s > 0; s >>= 1) {
        if (tid < s) {
            smn[tid] = fminf(smn[tid], smn[tid + s]);
            smx[tid] = fmaxf(smx[tid], smx[tid + s]);
        }
        __syncthreads();
    }
    if (tid == 0) { ws[0] = smn[0]; ws[1] = smx[0]; }
}

// ---------------- kernel 2: fused per-row KL + MLP ----------------
// One block (256 threads) per row. Row lives in registers (8 x float4 per
// thread). Histograms are 32-way replicated in LDS to kill same-address
// atomic serialization. Wave 0 finishes KL and the 32-wide MLP.
__global__ __launch_bounds__(256)
void kl_fused_kernel(const float* __restrict__ cur,
                     const float* __restrict__ ref,
                     const float* __restrict__ ws,
                     const float* __restrict__ w1,
                     const float* __restrict__ b1,
                     const float* __restrict__ w2,
                     const float* __restrict__ b2,
                     float* __restrict__ kl_out,
                     float* __restrict__ enc_out) {
    __shared__ unsigned hp[NC * NB], hq[NC * NB];
    __shared__ float rmn[4], rmx[4];

    const int b    = blockIdx.x;
    const int tid  = threadIdx.x;
    const int lane = tid & 63;
    const int wave = tid >> 6;

    for (int i = tid; i < NC * NB; i += 256) { hp[i] = 0u; hq[i] = 0u; }

    // ---- load row into registers, per-thread min/max ----
    const float4* src = (const float4*)(cur + (size_t)b * T_LEN);
    float4 v[8];
    float mn = 3.0e38f, mx = -3.0e38f;
    #pragma unroll
    for (int i = 0; i < 8; ++i) {
        v[i] = src[tid + i * 256];
        mn = fminf(mn, fminf(fminf(v[i].x, v[i].y), fminf(v[i].z, v[i].w)));
        mx = fmaxf(mx, fmaxf(fmaxf(v[i].x, v[i].y), fmaxf(v[i].z, v[i].w)));
    }
    #pragma unroll
    for (int off = 32; off > 0; off >>= 1) {
        mn = fminf(mn, __shfl_xor(mn, off));
        mx = fmaxf(mx, __shfl_xor(mx, off));
    }
    if (lane == 0) { rmn[wave] = mn; rmx[wave] = mx; }
    __syncthreads();   // also covers histogram zero-init

    const float cmin = fminf(fminf(rmn[0], rmn[1]), fminf(rmn[2], rmn[3]));
    const float cmax = fmaxf(fmaxf(rmx[0], rmx[1]), fmaxf(rmx[2], rmx[3]));
    const float lo = fminf(ws[0], cmin);
    const float hi = fmaxf(ws[1], cmax);
    const float width = (hi - lo) / (float)NB;

    // ---- histogram current row (from registers) ----
    unsigned* myq = hq + (tid & (NC - 1)) * NB;
    #pragma unroll
    for (int i = 0; i < 8; ++i) {
        int i0 = min(max((int)floorf((v[i].x - lo) / width), 0), NB - 1);
        int i1 = min(max((int)floorf((v[i].y - lo) / width), 0), NB - 1);
        int i2 = min(max((int)floorf((v[i].z - lo) / width), 0), NB - 1);
        int i3 = min(max((int)floorf((v[i].w - lo) / width), 0), NB - 1);
        atomicAdd(&myq[i0], 1u);
        atomicAdd(&myq[i1], 1u);
        atomicAdd(&myq[i2], 1u);
        atomicAdd(&myq[i3], 1u);
    }
    // ---- histogram reference (global; L1/L2-hot, 32 KB shared by all) ----
    unsigned* myp = hp + (tid & (NC - 1)) * NB;
    const float4* r4 = (const float4*)ref;
    #pragma unroll
    for (int i = 0; i < 8; ++i) {
        float4 rv = r4[tid + i * 256];
        int i0 = min(max((int)floorf((rv.x - lo) / width), 0), NB - 1);
        int i1 = min(max((int)floorf((rv.y - lo) / width), 0), NB - 1);
        int i2 = min(max((int)floorf((rv.z - lo) / width), 0), NB - 1);
        int i3 = min(max((int)floorf((rv.w - lo) / width), 0), NB - 1);
        atomicAdd(&myp[i0], 1u);
        atomicAdd(&myp[i1], 1u);
        atomicAdd(&myp[i2], 1u);
        atomicAdd(&myp[i3], 1u);
    }
    __syncthreads();

    // ---- KL over 49 bins + fused MLP on wave 0 ----
    if (tid < 64) {
        const bool act = tid < NB;
        float p = 0.0f, q = 0.0f;
        if (act) {
            unsigned sp = 0u, sq = 0u;
            #pragma unroll
            for (int c = 0; c < NC; ++c) { sp += hp[c * NB + tid]; sq += hq[c * NB + tid]; }
            const float inv = 1.0f / ((float)T_LEN * width);
            p = (float)sp * inv + EPSF;
            q = (float)sq * inv + EPSF;
        }
        float P = p, Q = q;
        #pragma unroll
        for (int off = 32; off > 0; off >>= 1) {
            P += __shfl_xor(P, off);
            Q += __shfl_xor(Q, off);
        }
        float term = 0.0f;
        if (act) {
            const float pn = p / P;
            const float qn = q / Q;
            term = pn * logf(pn / qn);
        }
        #pragma unroll
        for (int off = 32; off > 0; off >>= 1) term += __shfl_xor(term, off);
        // after the butterfly every lane of wave 0 holds the full KL value
        if (tid == 0) kl_out[b] = term;

        if (tid < HDIM) {
            const float k = term;
            float acc = b2[tid];
            #pragma unroll
            for (int t = 0; t < HDIM; ++t) {
                float h = fmaxf(fmaf(k, w1[t], b1[t]), 0.0f);
                acc = fmaf(h, w2[tid * HDIM + t], acc);
            }
            enc_out[(size_t)b * HDIM + tid] = acc;
        }
    }
}

extern "C" void kernel_launch(void* const* d_in, const int* in_sizes, int n_in,
                              void* d_out, int out_size, void* d_ws, size_t ws_size,
                              hipStream_t stream) {
    const float* cur = (const float*)d_in[0];
    const float* ref = (const float*)d_in[1];
    const float* w1  = (const float*)d_in[2];
    const float* b1  = (const float*)d_in[3];
    const float* w2  = (const float*)d_in[4];
    const float* b2  = (const float*)d_in[5];
    float* out = (float*)d_out;           // [0, B) = kl ; [B, B + B*H) = encoded
    float* ws  = (float*)d_ws;

    ref_minmax_kernel<<<1, 256, 0, stream>>>(ref, ws);
    kl_fused_kernel<<<B_ROWS, 256, 0, stream>>>(
        cur, ref, ws, w1, b1, w2, b2, out, out + B_ROWS);
}